// Round 18
// baseline (77.954 us; speedup 1.0000x reference)
//
#include <hip/hip_runtime.h>
#include <stdint.h>
#include <stddef.h>

// ---------------------------------------------------------------------------
// Pipeline: prep (Wt transpose + exp-bias table ONLY) -> qkv GEMM (x staged
//           f32->f16 into LDS once; 32-row tiles, 12 panels, 3 blocks/CU) ->
//           FUSED attention+out-proj.
//
// Round-18: qkv occupancy. r17 ledger: total 74.5 = attn 54.7 (floor) +
// prep 1.5 + qkv ~15 + gaps. qkv was 2 blocks/CU (64KB LDS) with x read
// twice (ch split). New shape: 32-row tiles x all 12 panels, grid 512,
// LDS 48KB (Xs 16 + Bs 32) -> 3 blocks/CU = 3 waves/SIMD; x read once.
// 4 waves split each 64-col panel into 16x32 quadrants.
// attn_out byte-identical to r16/r17 (54.5us).
//
// Compact bias: rel_index[i,j] = (yi-yj+31)*63 + (xi-xj+31); key tile kt is
// image row yj=kt => bias depends only on (h, dy, xi, xj):
// ebC[8][63][32][32] f16 = exp(bias), 1.008 MB, L2-resident.
//
// Permuted-K trick: QK^T mfma #1 loads K rows perm0(r)=8*(r>>2)+(r&3), #2
// perm0+4. S^T C-fragment lands exactly in the PV B-fragment layout; P never
// leaves the lane. No-max softmax safe: |scores| < ~1.5.
//
// Workspace map (bytes):
//   [0,8M)    Qh  [16][8][1024][32] f16   (SCALE*log2e folded via Wt)
//   [8M,16M)  Kh  [16][8][1024][32] f16
//   [16M,24M) Vt  [16][8][32][1024] f16   (transposed: PV A-operand rows)
//   [24M,..)  ebC [8][63][32][32] f16     (1.008 MB)
//   [48M,..)  Wt_qkv [768][256] f16, Wt_out [256][256] f16
// ---------------------------------------------------------------------------

typedef _Float16 f16;
typedef __attribute__((ext_vector_type(8))) _Float16 half8;
typedef __attribute__((ext_vector_type(4))) _Float16 half4;
typedef __attribute__((ext_vector_type(2))) __fp16 fp16x2;   // builtin-compatible
typedef __attribute__((ext_vector_type(4))) float f32x4;

#define MFMA16(a, b, c) __builtin_amdgcn_mfma_f32_16x16x32_f16((a), (b), (c), 0, 0, 0)

// ---------------- prep: Wt transposes + ebC (weights only) ----------------
__global__ __launch_bounds__(256) void prep_kernel(
    const float* __restrict__ W_qkv, const float* __restrict__ W_out,
    const float* __restrict__ bias_table,
    f16* __restrict__ Wtq, f16* __restrict__ Wto, f16* __restrict__ ebC)
{
  const float kLog2e = 1.4426950408889634f;
  const float kScale = 0.17677669529663687f * kLog2e;  // 32^-0.5 * log2(e)
  int tid = blockIdx.x * 256 + threadIdx.x;
  if (tid < 24576) {                       // Wt_qkv[c][k], c<768
    int c = tid >> 5;
    int k8 = (tid & 31) << 3;
    float s = (c < 256) ? kScale : 1.0f;   // fold softmax scale+log2e into Q
    f16* dst = Wtq + c * 256 + k8;
#pragma unroll
    for (int j = 0; j < 8; ++j)
      dst[j] = (f16)(W_qkv[(k8 + j) * 768 + c] * s);
  } else if (tid < 32768) {                // Wt_out[c][k], c<256
    int t = tid - 24576;
    int c = t >> 5;
    int k8 = (t & 31) << 3;
    f16* dst = Wto + c * 256 + k8;
#pragma unroll
    for (int j = 0; j < 8; ++j)
      dst[j] = (f16)W_out[(k8 + j) * 256 + c];
  } else if (tid < 97280) {                // ebC[h][dy][xi][xj] = exp(bias)
    int t = tid - 32768;                   // 0..64511
    int e = t * 8;
    int h = e / 64512;                     // 63*1024
    int r = e - h * 64512;
    int dy = r >> 10;
    int xi = (r >> 5) & 31;
    int xj0 = r & 31;                      // multiple of 8
    int base = dy * 63 + xi + 31;          // idx = base - xj
    f16* dst = ebC + e;
#pragma unroll
    for (int j = 0; j < 8; ++j)
      dst[j] = (f16)__expf(bias_table[(base - (xj0 + j)) * 8 + h]);
  }
}

// ---------------- QKV GEMM (32-row tiles, 12 panels, 3 blocks/CU) ----------
// grid 512, 256 threads = 4 waves. Wave w: rows (w&1)*16, cols (w>>1)*32 of
// each 64-col panel. LDS: Xs 16KB + Bs 32KB = 48KB.
__global__ __launch_bounds__(256, 3) void qkv_kernel(
    const float* __restrict__ x, const f16* __restrict__ Wt,
    f16* __restrict__ Qh, f16* __restrict__ Kh, f16* __restrict__ Vt)
{
  __shared__ f16 Xs[32 * 256];             // swizzled [row][k], 16 KB
  __shared__ f16 Bs[64 * 256];             // swizzled [col][k], 32 KB
  int mt = blockIdx.x;                     // 32-row tile
  int tid = threadIdx.x;
  int wave = tid >> 6, lane = tid & 63;
  int g = lane >> 4, q16 = lane & 15;
  int rw = (wave & 1) * 16;                // row group within tile
  int cw = (wave >> 1) * 32;               // col group within panel
  char* XsB = (char*)Xs;
  char* BsB = (char*)Bs;

  // phase 0: x (f32, HBM, read ONCE) -> Xs (f16, swizzled)
  const float* xg = x + (size_t)(mt * 32) * 256;
#pragma unroll
  for (int i = 0; i < 8; ++i) {
    int c = i * 256 + tid;                 // f32x4 chunk id, 0..2047
    int row = c >> 6;                      // 64 chunks per row
    int o8 = (c & 63) * 8;                 // byte offset within f16 row
    f32x4 v = *(const f32x4*)(xg + (size_t)c * 4);
    half4 hv;
#pragma unroll
    for (int j = 0; j < 4; ++j) hv[j] = (f16)v[j];
    *(half4*)(XsB + ((row * 512 + o8) ^ ((row & 7) << 4))) = hv;
  }

  // stage first B panel
  {
    const f16* WtG = Wt;
#pragma unroll
    for (int i = 0; i < 8; ++i) {
      int c = i * 256 + tid;               // 16B chunk id, 0..2047
      int row = c >> 5;
      int colb = (c & 31) << 4;
      half8 v = *(const half8*)(WtG + c * 8);
      *(half8*)(BsB + row * 512 + (colb ^ ((row & 7) << 4))) = v;
    }
  }
  __syncthreads();

  int rbase = mt * 32 + rw;
  for (int p = 0; p < 12; ++p) {
    int cbase = p * 64 + cw;
    f32x4 acc[2] = {};
#pragma unroll 2
    for (int kc = 0; kc < 8; ++kc) {
      int rowA = rw + q16;
      half8 af = *(const half8*)(XsB +
          ((rowA * 512 + kc * 64 + g * 16) ^ ((rowA & 7) << 4)));
#pragma unroll
      for (int cf = 0; cf < 2; ++cf) {
        int row = cw + cf * 16 + q16;
        int colb = kc * 64 + g * 16;
        half8 bf = *(const half8*)(BsB + row * 512 + (colb ^ ((row & 7) << 4)));
        acc[cf] = MFMA16(af, bf, acc[cf]);
      }
    }
    // write outputs for this quadrant
#pragma unroll
    for (int cf = 0; cf < 2; ++cf) {
      int c = cbase + cf * 16 + q16;
      int which = c >> 8, h = (c >> 5) & 7, d = c & 31;
      int m0 = rbase + g * 4;
      int b = m0 >> 10, n0 = m0 & 1023;    // 4 r's: same b, consecutive n
      size_t bh = (size_t)(b * 8 + h);
      if (which == 2) {                    // V^T: pack 4 consecutive n (8B)
        half4 vv;
#pragma unroll
        for (int r = 0; r < 4; ++r) vv[r] = (f16)acc[cf][r];
        *(half4*)(Vt + (((bh << 5) | d) << 10) + n0) = vv;
      } else {
        f16* base = (which == 0) ? Qh : Kh;
#pragma unroll
        for (int r = 0; r < 4; ++r)
          base[((bh << 10) | (n0 + r)) * 32 + d] = (f16)acc[cf][r];
      }
    }
    if (p < 11) {
      __syncthreads();                     // all waves done reading Bs
      const f16* WtG = Wt + (size_t)((p + 1) * 64) * 256;
#pragma unroll
      for (int i = 0; i < 8; ++i) {
        int c = i * 256 + tid;
        int row = c >> 5;
        int colb = (c & 31) << 4;
        half8 v = *(const half8*)(WtG + c * 8);
        *(half8*)(BsB + row * 512 + (colb ^ ((row & 7) << 4))) = v;
      }
      __syncthreads();
    }
  }
}

// ------------- FUSED flash attention + out projection ----------------------
// grid 256: b = bid&15 (XCD pin via b&7), qt = bid>>4. Block = 512 threads
// = 8 waves; wave w = head w, 64 q-rows [qt*64, qt*64+64). Main kt loop is
// r11-identical per wave. Epilogue: O^T -> LDS (swizzled) -> 64x32 out slice.
__global__ __launch_bounds__(512) void attn_out_kernel(
    const f16* __restrict__ Qh, const f16* __restrict__ Kh,
    const f16* __restrict__ Vt, const f16* __restrict__ ebC,
    const f16* __restrict__ Wto, const float* __restrict__ b_out,
    float* __restrict__ out)
{
  __shared__ f16 Os[8 * 64 * 32];          // [head][qloc][d], XOR-swizzled
  int bid = blockIdx.x;
  int b = bid & 15;
  int qt = bid >> 4;
  int wave = threadIdx.x >> 6, lane = threadIdx.x & 63;
  int g = lane >> 4, q16 = lane & 15;
  int h = wave;
  int bh = b * 8 + h;
  int qbase = qt * 64;
  const f16* Qb = Qh + ((size_t)bh << 15);
  const f16* Kb = Kh + ((size_t)bh << 15);
  const f16* Vb = Vt + ((size_t)bh << 15);

  // 4 Q fragments: frag f covers qrows qbase + f*16 + q16 (col=q16, k=8g+i)
  half8 qf0 = *(const half8*)(Qb + (size_t)(qbase +  0 + q16) * 32 + g * 8);
  half8 qf1 = *(const half8*)(Qb + (size_t)(qbase + 16 + q16) * 32 + g * 8);
  half8 qf2 = *(const half8*)(Qb + (size_t)(qbase + 32 + q16) * 32 + g * 8);
  half8 qf3 = *(const half8*)(Qb + (size_t)(qbase + 48 + q16) * 32 + g * 8);

  // permuted K rows: s0 covers keys 8g+{0..3}, s1 keys 8g+4+{0..3}
  int kr0 = ((q16 >> 2) << 3) | (q16 & 3);   // perm0(q16)
  const f16* Kp0 = Kb + kr0 * 32 + g * 8;
  const f16* Kp1 = Kp0 + 4 * 32;             // perm1 = perm0 + 4 rows
  const f16* Vp0 = Vb + (size_t)q16 * 1024 + g * 8;          // V^T d=0..15
  const f16* Vp1 = Vb + (size_t)(16 + q16) * 1024 + g * 8;   // d=16..31
  // ebC[h][dy][xi][xj]: frag0 (yi0, xi=q16); frag1 xi=16+q16 (+512 elems);
  // frag2 yi0+1 (+1024); frag3 (+1536). dy = yi0+31-kt => -1024 elems per kt.
  int yi0 = qbase >> 5;
  const f16* Bp = ebC + ((((h * 63 + yi0 + 31) * 32 + q16) << 5) + g * 8);

  f32x4 o0a = {0.f,0.f,0.f,0.f}, o1a = {0.f,0.f,0.f,0.f};
  f32x4 o0b = {0.f,0.f,0.f,0.f}, o1b = {0.f,0.f,0.f,0.f};
  f32x4 o0c = {0.f,0.f,0.f,0.f}, o1c = {0.f,0.f,0.f,0.f};
  f32x4 o0d = {0.f,0.f,0.f,0.f}, o1d = {0.f,0.f,0.f,0.f};
  float lsa = 0.f, lsb = 0.f, lsc = 0.f, lsd = 0.f;
  const fp16x2 one2 = {(__fp16)1.0f, (__fp16)1.0f};
  (void)one2;

#if __has_builtin(__builtin_amdgcn_fdot2)
#define LSUM(LS, PU)                                                         \
    LS = __builtin_amdgcn_fdot2(PU.h2[0], one2, LS, false);                  \
    LS = __builtin_amdgcn_fdot2(PU.h2[1], one2, LS, false);                  \
    LS = __builtin_amdgcn_fdot2(PU.h2[2], one2, LS, false);                  \
    LS = __builtin_amdgcn_fdot2(PU.h2[3], one2, LS, false);
#else
#define LSUM(LS, PU)                                                         \
    _Pragma("unroll") for (int i = 0; i < 8; ++i) { LS += (float)PU.h8[i]; }
#endif

#define FRAG_BODY(QF, K0, K1, V0, V1, EB, O0, O1, LS)                        \
  {                                                                          \
    const f32x4 zz = {0.f, 0.f, 0.f, 0.f};                                   \
    f32x4 s0 = MFMA16(K0, QF, zz);   /* keys 8g+0..3 of col q16 */           \
    f32x4 s1 = MFMA16(K1, QF, zz);   /* keys 8g+4..7 */                      \
    union { fp16x2 h2[4]; half8 h8; } pu, eu;                                \
    eu.h8 = EB;                                                              \
    pu.h2[0] = __builtin_amdgcn_cvt_pkrtz(                                   \
        __builtin_amdgcn_exp2f(s0[0]), __builtin_amdgcn_exp2f(s0[1]));       \
    pu.h2[1] = __builtin_amdgcn_cvt_pkrtz(                                   \
        __builtin_amdgcn_exp2f(s0[2]), __builtin_amdgcn_exp2f(s0[3]));       \
    pu.h2[2] = __builtin_amdgcn_cvt_pkrtz(                                   \
        __builtin_amdgcn_exp2f(s1[0]), __builtin_amdgcn_exp2f(s1[1]));       \
    pu.h2[3] = __builtin_amdgcn_cvt_pkrtz(                                   \
        __builtin_amdgcn_exp2f(s1[2]), __builtin_amdgcn_exp2f(s1[3]));       \
    pu.h2[0] *= eu.h2[0];  pu.h2[1] *= eu.h2[1];   /* v_pk_mul_f16 */        \
    pu.h2[2] *= eu.h2[2];  pu.h2[3] *= eu.h2[3];                             \
    LSUM(LS, pu)                                                             \
    O0 = MFMA16(V0, pu.h8, O0);      /* O^T[4g+r][q16] */                    \
    O1 = MFMA16(V1, pu.h8, O1);      /* O^T[16+4g+r][q16] */                 \
  }

  half8 kA0 = *(const half8*)Kp0;
  half8 kA1 = *(const half8*)Kp1;
  half8 vA0 = *(const half8*)Vp0;
  half8 vA1 = *(const half8*)Vp1;
  half8 bA0 = *(const half8*)(Bp);
  half8 bA1 = *(const half8*)(Bp + 512);
  half8 bA2 = *(const half8*)(Bp + 1024);
  half8 bA3 = *(const half8*)(Bp + 1536);

  for (int kt = 0; kt < 31; ++kt) {
    size_t ko = (size_t)(kt + 1) * 1024;   // K: 32 keys * 32 d
    int    co = (kt + 1) * 32;             // V^T column offset
    const f16* Bn = Bp - ko;               // dy decreases with kt
    half8 kB0 = *(const half8*)(Kp0 + ko);
    half8 kB1 = *(const half8*)(Kp1 + ko);
    half8 vB0 = *(const half8*)(Vp0 + co);
    half8 vB1 = *(const half8*)(Vp1 + co);
    half8 bB0 = *(const half8*)(Bn);
    half8 bB1 = *(const half8*)(Bn + 512);
    half8 bB2 = *(const half8*)(Bn + 1024);
    half8 bB3 = *(const half8*)(Bn + 1536);
    // Pin the prefetch issue BEFORE the compute of tile kt.
    __builtin_amdgcn_sched_barrier(0);
    FRAG_BODY(qf0, kA0, kA1, vA0, vA1, bA0, o0a, o1a, lsa);
    FRAG_BODY(qf1, kA0, kA1, vA0, vA1, bA1, o0b, o1b, lsb);
    FRAG_BODY(qf2, kA0, kA1, vA0, vA1, bA2, o0c, o1c, lsc);
    FRAG_BODY(qf3, kA0, kA1, vA0, vA1, bA3, o0d, o1d, lsd);
    kA0 = kB0; kA1 = kB1; vA0 = vB0; vA1 = vB1;
    bA0 = bB0; bA1 = bB1; bA2 = bB2; bA3 = bB3;
  }
  FRAG_BODY(qf0, kA0, kA1, vA0, vA1, bA0, o0a, o1a, lsa);
  FRAG_BODY(qf1, kA0, kA1, vA0, vA1, bA1, o0b, o1b, lsb);
  FRAG_BODY(qf2, kA0, kA1, vA0, vA1, bA2, o0c, o1c, lsc);
  FRAG_BODY(qf3, kA0, kA1, vA0, vA1, bA3, o0d, o1d, lsd);
#undef FRAG_BODY
#undef LSUM

  // ---- epilogue 1: normalized O^T -> LDS (swizzled) ----
  char* OsB = (char*)Os + h * 4096;
#define FRAG_OUT(O0, O1, LS, F)                                              \
  {                                                                          \
    float l = LS;                                                            \
    l += __shfl_xor(l, 16);                                                  \
    l += __shfl_xor(l, 32);                                                  \
    float invl = 1.0f / l;                                                   \
    int floc = (F) * 16 + q16;                                               \
    int swz = (floc & 7) << 4;                                               \
    half4 w0, w1;                                                            \
    _Pragma("unroll") for (int r = 0; r < 4; ++r) {                          \
      w0[r] = (f16)(O0[r] * invl); w1[r] = (f16)(O1[r] * invl);              \
    }                                                                        \
    *(half4*)(OsB + ((floc * 64 + g * 8) ^ swz)) = w0;                       \
    *(half4*)(OsB + ((floc * 64 + 32 + g * 8) ^ swz)) = w1;                  \
  }
  FRAG_OUT(o0a, o1a, lsa, 0);
  FRAG_OUT(o0b, o1b, lsb, 1);
  FRAG_OUT(o0c, o1c, lsc, 2);
  FRAG_OUT(o0d, o1d, lsd, 3);
#undef FRAG_OUT

  __syncthreads();

  // ---- epilogue 2: out-proj slice, cols [wave*32, wave*32+32) ----
  int cb = wave * 32;
  float bias0 = b_out[cb + q16];
  float bias1 = b_out[cb + 16 + q16];
  f32x4 acc[4][2] = {};
  const char* OsA = (const char*)Os;
#pragma unroll
  for (int kc = 0; kc < 8; ++kc) {         // k-chunk = head kc, d = 8g..+7
    half8 bf0 = *(const half8*)(Wto + (size_t)(cb + q16) * 256 + kc * 32 + g * 8);
    half8 bf1 = *(const half8*)(Wto + (size_t)(cb + 16 + q16) * 256 + kc * 32 + g * 8);
#pragma unroll
    for (int mf = 0; mf < 4; ++mf) {
      int row = mf * 16 + q16;
      half8 af = *(const half8*)(OsA + kc * 4096 +
                                 ((row * 64 + g * 16) ^ ((row & 7) << 4)));
      acc[mf][0] = MFMA16(af, bf0, acc[mf][0]);
      acc[mf][1] = MFMA16(af, bf1, acc[mf][1]);
    }
  }

#pragma unroll
  for (int mf = 0; mf < 4; ++mf) {
#pragma unroll
    for (int cf = 0; cf < 2; ++cf) {
      int c = cb + cf * 16 + q16;
      float bias = cf ? bias1 : bias0;
#pragma unroll
      for (int r = 0; r < 4; ++r) {
        int mm = (b << 10) + qbase + mf * 16 + g * 4 + r;
        out[(size_t)mm * 256 + c] = acc[mf][cf][r] + bias;
      }
    }
  }
}

extern "C" void kernel_launch(void* const* d_in, const int* in_sizes, int n_in,
                              void* d_out, int out_size, void* d_ws, size_t ws_size,
                              hipStream_t stream) {
  (void)in_sizes; (void)n_in; (void)out_size; (void)ws_size;
  const float* x        = (const float*)d_in[0];
  const float* W_qkv    = (const float*)d_in[1];
  const float* W_out    = (const float*)d_in[2];
  const float* b_out    = (const float*)d_in[3];
  const float* bias_tab = (const float*)d_in[4];
  float* out = (float*)d_out;
  char* ws = (char*)d_ws;

  f16* Qh  = (f16*)(ws);
  f16* Kh  = (f16*)(ws + (size_t)(8u  << 20));
  f16* Vt  = (f16*)(ws + (size_t)(16u << 20));
  f16* ebC = (f16*)(ws + (size_t)(24u << 20));
  f16* Wtq = (f16*)(ws + (size_t)(48u << 20));
  f16* Wto = (f16*)(ws + (size_t)(48u << 20) + 768 * 256 * 2);

  hipLaunchKernelGGL(prep_kernel, dim3(380), dim3(256), 0, stream,
                     W_qkv, W_out, bias_tab, Wtq, Wto, ebC);
  hipLaunchKernelGGL(qkv_kernel, dim3(512), dim3(256), 0, stream,
                     x, Wtq, Qh, Kh, Vt);
  hipLaunchKernelGGL(attn_out_kernel, dim3(256), dim3(512), 0, stream,
                     Qh, Kh, Vt, ebC, Wto, b_out, out);
}

// Round 19
// 74.527 us; speedup vs baseline: 1.0460x; 1.0460x over previous
//
#include <hip/hip_runtime.h>
#include <stdint.h>
#include <stddef.h>

// ---------------------------------------------------------------------------
// Pipeline: prep (Wt transpose + exp-bias table ONLY) -> qkv GEMM (x staged
//           f32->f16 into LDS once per block) -> FUSED attention+out-proj.
//
// Round-19: REVERT to r17 (best: 74.5us). r18's qkv reshape (32-row tiles,
// 12 panels, 3 blocks/CU) regressed to 78.0: halved MFMA-per-sync (8 vs 16),
// doubled barriers, more B restage traffic. Final configuration:
//   * qkv: grid (256,2), 4 waves x 16 rows, LDS 64KB (Xs 32 + Bs 32),
//     x read once per block and converted in-LDS.
//   * attn_out: fused flash-attention + out-projection (r16), 8 waves =
//     8 heads x 64 q-rows, O^T through swizzled LDS, 64x32 out slices.
//   * attn floor 54.7us established over r9-r13 (VALU cut, kt-split,
//     ping-pong+setprio, 32q/wave: all neutral-to-negative).
//
// Compact bias: rel_index[i,j] = (yi-yj+31)*63 + (xi-xj+31); key tile kt is
// image row yj=kt => bias depends only on (h, dy, xi, xj):
// ebC[8][63][32][32] f16 = exp(bias), 1.008 MB, L2-resident.
//
// Permuted-K trick: QK^T mfma #1 loads K rows perm0(r)=8*(r>>2)+(r&3), #2
// perm0+4. S^T C-fragment lands exactly in the PV B-fragment layout; P never
// leaves the lane. No-max softmax safe: |scores| < ~1.5.
//
// Workspace map (bytes):
//   [0,8M)    Qh  [16][8][1024][32] f16   (SCALE*log2e folded via Wt)
//   [8M,16M)  Kh  [16][8][1024][32] f16
//   [16M,24M) Vt  [16][8][32][1024] f16   (transposed: PV A-operand rows)
//   [24M,..)  ebC [8][63][32][32] f16     (1.008 MB)
//   [48M,..)  Wt_qkv [768][256] f16, Wt_out [256][256] f16
// ---------------------------------------------------------------------------

typedef _Float16 f16;
typedef __attribute__((ext_vector_type(8))) _Float16 half8;
typedef __attribute__((ext_vector_type(4))) _Float16 half4;
typedef __attribute__((ext_vector_type(2))) __fp16 fp16x2;   // builtin-compatible
typedef __attribute__((ext_vector_type(4))) float f32x4;

#define MFMA16(a, b, c) __builtin_amdgcn_mfma_f32_16x16x32_f16((a), (b), (c), 0, 0, 0)

// ---------------- prep: Wt transposes + ebC (weights only) ----------------
__global__ __launch_bounds__(256) void prep_kernel(
    const float* __restrict__ W_qkv, const float* __restrict__ W_out,
    const float* __restrict__ bias_table,
    f16* __restrict__ Wtq, f16* __restrict__ Wto, f16* __restrict__ ebC)
{
  const float kLog2e = 1.4426950408889634f;
  const float kScale = 0.17677669529663687f * kLog2e;  // 32^-0.5 * log2(e)
  int tid = blockIdx.x * 256 + threadIdx.x;
  if (tid < 24576) {                       // Wt_qkv[c][k], c<768
    int c = tid >> 5;
    int k8 = (tid & 31) << 3;
    float s = (c < 256) ? kScale : 1.0f;   // fold softmax scale+log2e into Q
    f16* dst = Wtq + c * 256 + k8;
#pragma unroll
    for (int j = 0; j < 8; ++j)
      dst[j] = (f16)(W_qkv[(k8 + j) * 768 + c] * s);
  } else if (tid < 32768) {                // Wt_out[c][k], c<256
    int t = tid - 24576;
    int c = t >> 5;
    int k8 = (t & 31) << 3;
    f16* dst = Wto + c * 256 + k8;
#pragma unroll
    for (int j = 0; j < 8; ++j)
      dst[j] = (f16)W_out[(k8 + j) * 256 + c];
  } else if (tid < 97280) {                // ebC[h][dy][xi][xj] = exp(bias)
    int t = tid - 32768;                   // 0..64511
    int e = t * 8;
    int h = e / 64512;                     // 63*1024
    int r = e - h * 64512;
    int dy = r >> 10;
    int xi = (r >> 5) & 31;
    int xj0 = r & 31;                      // multiple of 8
    int base = dy * 63 + xi + 31;          // idx = base - xj
    f16* dst = ebC + e;
#pragma unroll
    for (int j = 0; j < 8; ++j)
      dst[j] = (f16)__expf(bias_table[(base - (xj0 + j)) * 8 + h]);
  }
}

// ---------------- QKV GEMM (x staged to LDS once, 64 rows x 384 cols) ------
// grid (256,2), 256 threads = 4 waves x 16 rows. LDS: Xs 32KB + Bs 32KB.
__global__ __launch_bounds__(256, 2) void qkv_kernel(
    const float* __restrict__ x, const f16* __restrict__ Wt,
    f16* __restrict__ Qh, f16* __restrict__ Kh, f16* __restrict__ Vt)
{
  __shared__ f16 Xs[64 * 256];             // swizzled [row][k], 32 KB
  __shared__ f16 Bs[64 * 256];             // swizzled [col][k], 32 KB
  int mt = blockIdx.x;                     // 64-row tile
  int ch = blockIdx.y;                     // column half (6 panels of 64)
  int tid = threadIdx.x;
  int wave = tid >> 6, lane = tid & 63;
  int g = lane >> 4, q16 = lane & 15;
  char* XsB = (char*)Xs;
  char* BsB = (char*)Bs;

  // phase 0: x (f32, HBM, read ONCE) -> Xs (f16, swizzled)
  const float* xg = x + (size_t)(mt * 64) * 256;
#pragma unroll
  for (int i = 0; i < 16; ++i) {
    int c = i * 256 + tid;                 // f32x4 chunk id, 0..4095
    int row = c >> 6;                      // 64 chunks per row
    int o8 = (c & 63) * 8;                 // byte offset within f16 row
    f32x4 v = *(const f32x4*)(xg + (size_t)c * 4);
    half4 hv;
#pragma unroll
    for (int j = 0; j < 4; ++j) hv[j] = (f16)v[j];
    *(half4*)(XsB + ((row * 512 + o8) ^ ((row & 7) << 4))) = hv;
  }

  // stage first B panel
  {
    const f16* WtG = Wt + (size_t)(ch * 384) * 256;
#pragma unroll
    for (int i = 0; i < 8; ++i) {
      int c = i * 256 + tid;               // 16B chunk id, 0..2047
      int row = c >> 5;
      int colb = (c & 31) << 4;
      half8 v = *(const half8*)(WtG + c * 8);
      *(half8*)(BsB + row * 512 + (colb ^ ((row & 7) << 4))) = v;
    }
  }
  __syncthreads();

  int rbase = mt * 64 + wave * 16;
  for (int p = 0; p < 6; ++p) {
    int cbase = ch * 384 + p * 64;
    f32x4 acc[4] = {};
#pragma unroll 2
    for (int kc = 0; kc < 8; ++kc) {
      int rowA = wave * 16 + q16;
      half8 af = *(const half8*)(XsB +
          ((rowA * 512 + kc * 64 + g * 16) ^ ((rowA & 7) << 4)));
#pragma unroll
      for (int cf = 0; cf < 4; ++cf) {
        int row = cf * 16 + q16;
        int colb = kc * 64 + g * 16;
        half8 bf = *(const half8*)(BsB + row * 512 + (colb ^ ((row & 7) << 4)));
        acc[cf] = MFMA16(af, bf, acc[cf]);
      }
    }
    // write outputs for this panel
#pragma unroll
    for (int cf = 0; cf < 4; ++cf) {
      int c = cbase + cf * 16 + q16;
      int which = c >> 8, h = (c >> 5) & 7, d = c & 31;
      int m0 = rbase + g * 4;
      int b = m0 >> 10, n0 = m0 & 1023;    // 4 r's: same b, consecutive n
      size_t bh = (size_t)(b * 8 + h);
      if (which == 2) {                    // V^T: pack 4 consecutive n (8B)
        half4 vv;
#pragma unroll
        for (int r = 0; r < 4; ++r) vv[r] = (f16)acc[cf][r];
        *(half4*)(Vt + (((bh << 5) | d) << 10) + n0) = vv;
      } else {
        f16* base = (which == 0) ? Qh : Kh;
#pragma unroll
        for (int r = 0; r < 4; ++r)
          base[((bh << 10) | (n0 + r)) * 32 + d] = (f16)acc[cf][r];
      }
    }
    if (p < 5) {
      __syncthreads();                     // all waves done reading Bs
      const f16* WtG = Wt + (size_t)(ch * 384 + (p + 1) * 64) * 256;
#pragma unroll
      for (int i = 0; i < 8; ++i) {
        int c = i * 256 + tid;
        int row = c >> 5;
        int colb = (c & 31) << 4;
        half8 v = *(const half8*)(WtG + c * 8);
        *(half8*)(BsB + row * 512 + (colb ^ ((row & 7) << 4))) = v;
      }
      __syncthreads();
    }
  }
}

// ------------- FUSED flash attention + out projection ----------------------
// grid 256: b = bid&15 (XCD pin via b&7), qt = bid>>4. Block = 512 threads
// = 8 waves; wave w = head w, 64 q-rows [qt*64, qt*64+64). Main kt loop is
// r11-identical per wave. Epilogue: O^T -> LDS (swizzled) -> 64x32 out slice.
__global__ __launch_bounds__(512) void attn_out_kernel(
    const f16* __restrict__ Qh, const f16* __restrict__ Kh,
    const f16* __restrict__ Vt, const f16* __restrict__ ebC,
    const f16* __restrict__ Wto, const float* __restrict__ b_out,
    float* __restrict__ out)
{
  __shared__ f16 Os[8 * 64 * 32];          // [head][qloc][d], XOR-swizzled
  int bid = blockIdx.x;
  int b = bid & 15;
  int qt = bid >> 4;
  int wave = threadIdx.x >> 6, lane = threadIdx.x & 63;
  int g = lane >> 4, q16 = lane & 15;
  int h = wave;
  int bh = b * 8 + h;
  int qbase = qt * 64;
  const f16* Qb = Qh + ((size_t)bh << 15);
  const f16* Kb = Kh + ((size_t)bh << 15);
  const f16* Vb = Vt + ((size_t)bh << 15);

  // 4 Q fragments: frag f covers qrows qbase + f*16 + q16 (col=q16, k=8g+i)
  half8 qf0 = *(const half8*)(Qb + (size_t)(qbase +  0 + q16) * 32 + g * 8);
  half8 qf1 = *(const half8*)(Qb + (size_t)(qbase + 16 + q16) * 32 + g * 8);
  half8 qf2 = *(const half8*)(Qb + (size_t)(qbase + 32 + q16) * 32 + g * 8);
  half8 qf3 = *(const half8*)(Qb + (size_t)(qbase + 48 + q16) * 32 + g * 8);

  // permuted K rows: s0 covers keys 8g+{0..3}, s1 keys 8g+4+{0..3}
  int kr0 = ((q16 >> 2) << 3) | (q16 & 3);   // perm0(q16)
  const f16* Kp0 = Kb + kr0 * 32 + g * 8;
  const f16* Kp1 = Kp0 + 4 * 32;             // perm1 = perm0 + 4 rows
  const f16* Vp0 = Vb + (size_t)q16 * 1024 + g * 8;          // V^T d=0..15
  const f16* Vp1 = Vb + (size_t)(16 + q16) * 1024 + g * 8;   // d=16..31
  // ebC[h][dy][xi][xj]: frag0 (yi0, xi=q16); frag1 xi=16+q16 (+512 elems);
  // frag2 yi0+1 (+1024); frag3 (+1536). dy = yi0+31-kt => -1024 elems per kt.
  int yi0 = qbase >> 5;
  const f16* Bp = ebC + ((((h * 63 + yi0 + 31) * 32 + q16) << 5) + g * 8);

  f32x4 o0a = {0.f,0.f,0.f,0.f}, o1a = {0.f,0.f,0.f,0.f};
  f32x4 o0b = {0.f,0.f,0.f,0.f}, o1b = {0.f,0.f,0.f,0.f};
  f32x4 o0c = {0.f,0.f,0.f,0.f}, o1c = {0.f,0.f,0.f,0.f};
  f32x4 o0d = {0.f,0.f,0.f,0.f}, o1d = {0.f,0.f,0.f,0.f};
  float lsa = 0.f, lsb = 0.f, lsc = 0.f, lsd = 0.f;
  const fp16x2 one2 = {(__fp16)1.0f, (__fp16)1.0f};
  (void)one2;

#if __has_builtin(__builtin_amdgcn_fdot2)
#define LSUM(LS, PU)                                                         \
    LS = __builtin_amdgcn_fdot2(PU.h2[0], one2, LS, false);                  \
    LS = __builtin_amdgcn_fdot2(PU.h2[1], one2, LS, false);                  \
    LS = __builtin_amdgcn_fdot2(PU.h2[2], one2, LS, false);                  \
    LS = __builtin_amdgcn_fdot2(PU.h2[3], one2, LS, false);
#else
#define LSUM(LS, PU)                                                         \
    _Pragma("unroll") for (int i = 0; i < 8; ++i) { LS += (float)PU.h8[i]; }
#endif

#define FRAG_BODY(QF, K0, K1, V0, V1, EB, O0, O1, LS)                        \
  {                                                                          \
    const f32x4 zz = {0.f, 0.f, 0.f, 0.f};                                   \
    f32x4 s0 = MFMA16(K0, QF, zz);   /* keys 8g+0..3 of col q16 */           \
    f32x4 s1 = MFMA16(K1, QF, zz);   /* keys 8g+4..7 */                      \
    union { fp16x2 h2[4]; half8 h8; } pu, eu;                                \
    eu.h8 = EB;                                                              \
    pu.h2[0] = __builtin_amdgcn_cvt_pkrtz(                                   \
        __builtin_amdgcn_exp2f(s0[0]), __builtin_amdgcn_exp2f(s0[1]));       \
    pu.h2[1] = __builtin_amdgcn_cvt_pkrtz(                                   \
        __builtin_amdgcn_exp2f(s0[2]), __builtin_amdgcn_exp2f(s0[3]));       \
    pu.h2[2] = __builtin_amdgcn_cvt_pkrtz(                                   \
        __builtin_amdgcn_exp2f(s1[0]), __builtin_amdgcn_exp2f(s1[1]));       \
    pu.h2[3] = __builtin_amdgcn_cvt_pkrtz(                                   \
        __builtin_amdgcn_exp2f(s1[2]), __builtin_amdgcn_exp2f(s1[3]));       \
    pu.h2[0] *= eu.h2[0];  pu.h2[1] *= eu.h2[1];   /* v_pk_mul_f16 */        \
    pu.h2[2] *= eu.h2[2];  pu.h2[3] *= eu.h2[3];                             \
    LSUM(LS, pu)                                                             \
    O0 = MFMA16(V0, pu.h8, O0);      /* O^T[4g+r][q16] */                    \
    O1 = MFMA16(V1, pu.h8, O1);      /* O^T[16+4g+r][q16] */                 \
  }

  half8 kA0 = *(const half8*)Kp0;
  half8 kA1 = *(const half8*)Kp1;
  half8 vA0 = *(const half8*)Vp0;
  half8 vA1 = *(const half8*)Vp1;
  half8 bA0 = *(const half8*)(Bp);
  half8 bA1 = *(const half8*)(Bp + 512);
  half8 bA2 = *(const half8*)(Bp + 1024);
  half8 bA3 = *(const half8*)(Bp + 1536);

  for (int kt = 0; kt < 31; ++kt) {
    size_t ko = (size_t)(kt + 1) * 1024;   // K: 32 keys * 32 d
    int    co = (kt + 1) * 32;             // V^T column offset
    const f16* Bn = Bp - ko;               // dy decreases with kt
    half8 kB0 = *(const half8*)(Kp0 + ko);
    half8 kB1 = *(const half8*)(Kp1 + ko);
    half8 vB0 = *(const half8*)(Vp0 + co);
    half8 vB1 = *(const half8*)(Vp1 + co);
    half8 bB0 = *(const half8*)(Bn);
    half8 bB1 = *(const half8*)(Bn + 512);
    half8 bB2 = *(const half8*)(Bn + 1024);
    half8 bB3 = *(const half8*)(Bn + 1536);
    // Pin the prefetch issue BEFORE the compute of tile kt.
    __builtin_amdgcn_sched_barrier(0);
    FRAG_BODY(qf0, kA0, kA1, vA0, vA1, bA0, o0a, o1a, lsa);
    FRAG_BODY(qf1, kA0, kA1, vA0, vA1, bA1, o0b, o1b, lsb);
    FRAG_BODY(qf2, kA0, kA1, vA0, vA1, bA2, o0c, o1c, lsc);
    FRAG_BODY(qf3, kA0, kA1, vA0, vA1, bA3, o0d, o1d, lsd);
    kA0 = kB0; kA1 = kB1; vA0 = vB0; vA1 = vB1;
    bA0 = bB0; bA1 = bB1; bA2 = bB2; bA3 = bB3;
  }
  FRAG_BODY(qf0, kA0, kA1, vA0, vA1, bA0, o0a, o1a, lsa);
  FRAG_BODY(qf1, kA0, kA1, vA0, vA1, bA1, o0b, o1b, lsb);
  FRAG_BODY(qf2, kA0, kA1, vA0, vA1, bA2, o0c, o1c, lsc);
  FRAG_BODY(qf3, kA0, kA1, vA0, vA1, bA3, o0d, o1d, lsd);
#undef FRAG_BODY
#undef LSUM

  // ---- epilogue 1: normalized O^T -> LDS (swizzled) ----
  char* OsB = (char*)Os + h * 4096;
#define FRAG_OUT(O0, O1, LS, F)                                              \
  {                                                                          \
    float l = LS;                                                            \
    l += __shfl_xor(l, 16);                                                  \
    l += __shfl_xor(l, 32);                                                  \
    float invl = 1.0f / l;                                                   \
    int floc = (F) * 16 + q16;                                               \
    int swz = (floc & 7) << 4;                                               \
    half4 w0, w1;                                                            \
    _Pragma("unroll") for (int r = 0; r < 4; ++r) {                          \
      w0[r] = (f16)(O0[r] * invl); w1[r] = (f16)(O1[r] * invl);              \
    }                                                                        \
    *(half4*)(OsB + ((floc * 64 + g * 8) ^ swz)) = w0;                       \
    *(half4*)(OsB + ((floc * 64 + 32 + g * 8) ^ swz)) = w1;                  \
  }
  FRAG_OUT(o0a, o1a, lsa, 0);
  FRAG_OUT(o0b, o1b, lsb, 1);
  FRAG_OUT(o0c, o1c, lsc, 2);
  FRAG_OUT(o0d, o1d, lsd, 3);
#undef FRAG_OUT

  __syncthreads();

  // ---- epilogue 2: out-proj slice, cols [wave*32, wave*32+32) ----
  int cb = wave * 32;
  float bias0 = b_out[cb + q16];
  float bias1 = b_out[cb + 16 + q16];
  f32x4 acc[4][2] = {};
  const char* OsA = (const char*)Os;
#pragma unroll
  for (int kc = 0; kc < 8; ++kc) {         // k-chunk = head kc, d = 8g..+7
    half8 bf0 = *(const half8*)(Wto + (size_t)(cb + q16) * 256 + kc * 32 + g * 8);
    half8 bf1 = *(const half8*)(Wto + (size_t)(cb + 16 + q16) * 256 + kc * 32 + g * 8);
#pragma unroll
    for (int mf = 0; mf < 4; ++mf) {
      int row = mf * 16 + q16;
      half8 af = *(const half8*)(OsA + kc * 4096 +
                                 ((row * 64 + g * 16) ^ ((row & 7) << 4)));
      acc[mf][0] = MFMA16(af, bf0, acc[mf][0]);
      acc[mf][1] = MFMA16(af, bf1, acc[mf][1]);
    }
  }

#pragma unroll
  for (int mf = 0; mf < 4; ++mf) {
#pragma unroll
    for (int cf = 0; cf < 2; ++cf) {
      int c = cb + cf * 16 + q16;
      float bias = cf ? bias1 : bias0;
#pragma unroll
      for (int r = 0; r < 4; ++r) {
        int mm = (b << 10) + qbase + mf * 16 + g * 4 + r;
        out[(size_t)mm * 256 + c] = acc[mf][cf][r] + bias;
      }
    }
  }
}

extern "C" void kernel_launch(void* const* d_in, const int* in_sizes, int n_in,
                              void* d_out, int out_size, void* d_ws, size_t ws_size,
                              hipStream_t stream) {
  (void)in_sizes; (void)n_in; (void)out_size; (void)ws_size;
  const float* x        = (const float*)d_in[0];
  const float* W_qkv    = (const float*)d_in[1];
  const float* W_out    = (const float*)d_in[2];
  const float* b_out    = (const float*)d_in[3];
  const float* bias_tab = (const float*)d_in[4];
  float* out = (float*)d_out;
  char* ws = (char*)d_ws;

  f16* Qh  = (f16*)(ws);
  f16* Kh  = (f16*)(ws + (size_t)(8u  << 20));
  f16* Vt  = (f16*)(ws + (size_t)(16u << 20));
  f16* ebC = (f16*)(ws + (size_t)(24u << 20));
  f16* Wtq = (f16*)(ws + (size_t)(48u << 20));
  f16* Wto = (f16*)(ws + (size_t)(48u << 20) + 768 * 256 * 2);

  hipLaunchKernelGGL(prep_kernel, dim3(380), dim3(256), 0, stream,
                     W_qkv, W_out, bias_tab, Wtq, Wto, ebC);
  hipLaunchKernelGGL(qkv_kernel, dim3(256, 2), dim3(256), 0, stream,
                     x, Wtq, Qh, Kh, Vt);
  hipLaunchKernelGGL(attn_out_kernel, dim3(256), dim3(512), 0, stream,
                     Qh, Kh, Vt, ebC, Wto, b_out, out);
}

// Round 20
// 68.039 us; speedup vs baseline: 1.1457x; 1.0954x over previous
//
#include <hip/hip_runtime.h>
#include <stdint.h>
#include <stddef.h>

// ---------------------------------------------------------------------------
// Pipeline: prep (Wt transpose + exp-bias table ONLY) -> qkv GEMM (x staged
//           f32->f16 into LDS once per block) -> FUSED attention+out-proj.
//
// Round-20: r19 + bias-register-reuse in the attn kt loop. Derivation:
// bias(frag2, kt+1) has dy-idx yi0+32-(kt+1) = yi0+31-kt = bias(frag0, kt)
// (same xi, same xj range); likewise frag3(kt+1)=frag1(kt). The rolling
// prefetch thus needs only 2 bias loads/kt (was 4): per-wave loads per kt
// drop 8 -> 6 on an L1-delivery-co-bound kernel (r13 evidence).
// All else identical to r17/r19 (74.5us reproduced twice).
//
// Compact bias: rel_index[i,j] = (yi-yj+31)*63 + (xi-xj+31); key tile kt is
// image row yj=kt => bias depends only on (h, dy, xi, xj):
// ebC[8][63][32][32] f16 = exp(bias), 1.008 MB, L2-resident.
//
// Permuted-K trick: QK^T mfma #1 loads K rows perm0(r)=8*(r>>2)+(r&3), #2
// perm0+4. S^T C-fragment lands exactly in the PV B-fragment layout; P never
// leaves the lane. No-max softmax safe: |scores| < ~1.5.
//
// Workspace map (bytes):
//   [0,8M)    Qh  [16][8][1024][32] f16   (SCALE*log2e folded via Wt)
//   [8M,16M)  Kh  [16][8][1024][32] f16
//   [16M,24M) Vt  [16][8][32][1024] f16   (transposed: PV A-operand rows)
//   [24M,..)  ebC [8][63][32][32] f16     (1.008 MB)
//   [48M,..)  Wt_qkv [768][256] f16, Wt_out [256][256] f16
// ---------------------------------------------------------------------------

typedef _Float16 f16;
typedef __attribute__((ext_vector_type(8))) _Float16 half8;
typedef __attribute__((ext_vector_type(4))) _Float16 half4;
typedef __attribute__((ext_vector_type(2))) __fp16 fp16x2;   // builtin-compatible
typedef __attribute__((ext_vector_type(4))) float f32x4;

#define MFMA16(a, b, c) __builtin_amdgcn_mfma_f32_16x16x32_f16((a), (b), (c), 0, 0, 0)

// ---------------- prep: Wt transposes + ebC (weights only) ----------------
__global__ __launch_bounds__(256) void prep_kernel(
    const float* __restrict__ W_qkv, const float* __restrict__ W_out,
    const float* __restrict__ bias_table,
    f16* __restrict__ Wtq, f16* __restrict__ Wto, f16* __restrict__ ebC)
{
  const float kLog2e = 1.4426950408889634f;
  const float kScale = 0.17677669529663687f * kLog2e;  // 32^-0.5 * log2(e)
  int tid = blockIdx.x * 256 + threadIdx.x;
  if (tid < 24576) {                       // Wt_qkv[c][k], c<768
    int c = tid >> 5;
    int k8 = (tid & 31) << 3;
    float s = (c < 256) ? kScale : 1.0f;   // fold softmax scale+log2e into Q
    f16* dst = Wtq + c * 256 + k8;
#pragma unroll
    for (int j = 0; j < 8; ++j)
      dst[j] = (f16)(W_qkv[(k8 + j) * 768 + c] * s);
  } else if (tid < 32768) {                // Wt_out[c][k], c<256
    int t = tid - 24576;
    int c = t >> 5;
    int k8 = (t & 31) << 3;
    f16* dst = Wto + c * 256 + k8;
#pragma unroll
    for (int j = 0; j < 8; ++j)
      dst[j] = (f16)W_out[(k8 + j) * 256 + c];
  } else if (tid < 97280) {                // ebC[h][dy][xi][xj] = exp(bias)
    int t = tid - 32768;                   // 0..64511
    int e = t * 8;
    int h = e / 64512;                     // 63*1024
    int r = e - h * 64512;
    int dy = r >> 10;
    int xi = (r >> 5) & 31;
    int xj0 = r & 31;                      // multiple of 8
    int base = dy * 63 + xi + 31;          // idx = base - xj
    f16* dst = ebC + e;
#pragma unroll
    for (int j = 0; j < 8; ++j)
      dst[j] = (f16)__expf(bias_table[(base - (xj0 + j)) * 8 + h]);
  }
}

// ---------------- QKV GEMM (x staged to LDS once, 64 rows x 384 cols) ------
// grid (256,2), 256 threads = 4 waves x 16 rows. LDS: Xs 32KB + Bs 32KB.
__global__ __launch_bounds__(256, 2) void qkv_kernel(
    const float* __restrict__ x, const f16* __restrict__ Wt,
    f16* __restrict__ Qh, f16* __restrict__ Kh, f16* __restrict__ Vt)
{
  __shared__ f16 Xs[64 * 256];             // swizzled [row][k], 32 KB
  __shared__ f16 Bs[64 * 256];             // swizzled [col][k], 32 KB
  int mt = blockIdx.x;                     // 64-row tile
  int ch = blockIdx.y;                     // column half (6 panels of 64)
  int tid = threadIdx.x;
  int wave = tid >> 6, lane = tid & 63;
  int g = lane >> 4, q16 = lane & 15;
  char* XsB = (char*)Xs;
  char* BsB = (char*)Bs;

  // phase 0: x (f32, HBM, read ONCE) -> Xs (f16, swizzled)
  const float* xg = x + (size_t)(mt * 64) * 256;
#pragma unroll
  for (int i = 0; i < 16; ++i) {
    int c = i * 256 + tid;                 // f32x4 chunk id, 0..4095
    int row = c >> 6;                      // 64 chunks per row
    int o8 = (c & 63) * 8;                 // byte offset within f16 row
    f32x4 v = *(const f32x4*)(xg + (size_t)c * 4);
    half4 hv;
#pragma unroll
    for (int j = 0; j < 4; ++j) hv[j] = (f16)v[j];
    *(half4*)(XsB + ((row * 512 + o8) ^ ((row & 7) << 4))) = hv;
  }

  // stage first B panel
  {
    const f16* WtG = Wt + (size_t)(ch * 384) * 256;
#pragma unroll
    for (int i = 0; i < 8; ++i) {
      int c = i * 256 + tid;               // 16B chunk id, 0..2047
      int row = c >> 5;
      int colb = (c & 31) << 4;
      half8 v = *(const half8*)(WtG + c * 8);
      *(half8*)(BsB + row * 512 + (colb ^ ((row & 7) << 4))) = v;
    }
  }
  __syncthreads();

  int rbase = mt * 64 + wave * 16;
  for (int p = 0; p < 6; ++p) {
    int cbase = ch * 384 + p * 64;
    f32x4 acc[4] = {};
#pragma unroll 2
    for (int kc = 0; kc < 8; ++kc) {
      int rowA = wave * 16 + q16;
      half8 af = *(const half8*)(XsB +
          ((rowA * 512 + kc * 64 + g * 16) ^ ((rowA & 7) << 4)));
#pragma unroll
      for (int cf = 0; cf < 4; ++cf) {
        int row = cf * 16 + q16;
        int colb = kc * 64 + g * 16;
        half8 bf = *(const half8*)(BsB + row * 512 + (colb ^ ((row & 7) << 4)));
        acc[cf] = MFMA16(af, bf, acc[cf]);
      }
    }
    // write outputs for this panel
#pragma unroll
    for (int cf = 0; cf < 4; ++cf) {
      int c = cbase + cf * 16 + q16;
      int which = c >> 8, h = (c >> 5) & 7, d = c & 31;
      int m0 = rbase + g * 4;
      int b = m0 >> 10, n0 = m0 & 1023;    // 4 r's: same b, consecutive n
      size_t bh = (size_t)(b * 8 + h);
      if (which == 2) {                    // V^T: pack 4 consecutive n (8B)
        half4 vv;
#pragma unroll
        for (int r = 0; r < 4; ++r) vv[r] = (f16)acc[cf][r];
        *(half4*)(Vt + (((bh << 5) | d) << 10) + n0) = vv;
      } else {
        f16* base = (which == 0) ? Qh : Kh;
#pragma unroll
        for (int r = 0; r < 4; ++r)
          base[((bh << 10) | (n0 + r)) * 32 + d] = (f16)acc[cf][r];
      }
    }
    if (p < 5) {
      __syncthreads();                     // all waves done reading Bs
      const f16* WtG = Wt + (size_t)(ch * 384 + (p + 1) * 64) * 256;
#pragma unroll
      for (int i = 0; i < 8; ++i) {
        int c = i * 256 + tid;
        int row = c >> 5;
        int colb = (c & 31) << 4;
        half8 v = *(const half8*)(WtG + c * 8);
        *(half8*)(BsB + row * 512 + (colb ^ ((row & 7) << 4))) = v;
      }
      __syncthreads();
    }
  }
}

// ------------- FUSED flash attention + out projection ----------------------
// grid 256: b = bid&15 (XCD pin via b&7), qt = bid>>4. Block = 512 threads
// = 8 waves; wave w = head w, 64 q-rows [qt*64, qt*64+64). Main kt loop is
// r11-identical per wave except bias-register-reuse (2 loads/kt, was 4).
// Epilogue: O^T -> LDS (swizzled) -> 64x32 out slice.
__global__ __launch_bounds__(512) void attn_out_kernel(
    const f16* __restrict__ Qh, const f16* __restrict__ Kh,
    const f16* __restrict__ Vt, const f16* __restrict__ ebC,
    const f16* __restrict__ Wto, const float* __restrict__ b_out,
    float* __restrict__ out)
{
  __shared__ f16 Os[8 * 64 * 32];          // [head][qloc][d], XOR-swizzled
  int bid = blockIdx.x;
  int b = bid & 15;
  int qt = bid >> 4;
  int wave = threadIdx.x >> 6, lane = threadIdx.x & 63;
  int g = lane >> 4, q16 = lane & 15;
  int h = wave;
  int bh = b * 8 + h;
  int qbase = qt * 64;
  const f16* Qb = Qh + ((size_t)bh << 15);
  const f16* Kb = Kh + ((size_t)bh << 15);
  const f16* Vb = Vt + ((size_t)bh << 15);

  // 4 Q fragments: frag f covers qrows qbase + f*16 + q16 (col=q16, k=8g+i)
  half8 qf0 = *(const half8*)(Qb + (size_t)(qbase +  0 + q16) * 32 + g * 8);
  half8 qf1 = *(const half8*)(Qb + (size_t)(qbase + 16 + q16) * 32 + g * 8);
  half8 qf2 = *(const half8*)(Qb + (size_t)(qbase + 32 + q16) * 32 + g * 8);
  half8 qf3 = *(const half8*)(Qb + (size_t)(qbase + 48 + q16) * 32 + g * 8);

  // permuted K rows: s0 covers keys 8g+{0..3}, s1 keys 8g+4+{0..3}
  int kr0 = ((q16 >> 2) << 3) | (q16 & 3);   // perm0(q16)
  const f16* Kp0 = Kb + kr0 * 32 + g * 8;
  const f16* Kp1 = Kp0 + 4 * 32;             // perm1 = perm0 + 4 rows
  const f16* Vp0 = Vb + (size_t)q16 * 1024 + g * 8;          // V^T d=0..15
  const f16* Vp1 = Vb + (size_t)(16 + q16) * 1024 + g * 8;   // d=16..31
  // ebC[h][dy][xi][xj]: frag0 (yi0, xi=q16); frag1 xi=16+q16 (+512 elems);
  // frag2 yi0+1 (+1024); frag3 (+1536). dy = yi0+31-kt => -1024 elems per kt.
  // Reuse identity: bias(frag2, kt+1) = bias(frag0, kt); frag3(kt+1)=frag1(kt).
  int yi0 = qbase >> 5;
  const f16* Bp = ebC + ((((h * 63 + yi0 + 31) * 32 + q16) << 5) + g * 8);

  f32x4 o0a = {0.f,0.f,0.f,0.f}, o1a = {0.f,0.f,0.f,0.f};
  f32x4 o0b = {0.f,0.f,0.f,0.f}, o1b = {0.f,0.f,0.f,0.f};
  f32x4 o0c = {0.f,0.f,0.f,0.f}, o1c = {0.f,0.f,0.f,0.f};
  f32x4 o0d = {0.f,0.f,0.f,0.f}, o1d = {0.f,0.f,0.f,0.f};
  float lsa = 0.f, lsb = 0.f, lsc = 0.f, lsd = 0.f;
  const fp16x2 one2 = {(__fp16)1.0f, (__fp16)1.0f};
  (void)one2;

#if __has_builtin(__builtin_amdgcn_fdot2)
#define LSUM(LS, PU)                                                         \
    LS = __builtin_amdgcn_fdot2(PU.h2[0], one2, LS, false);                  \
    LS = __builtin_amdgcn_fdot2(PU.h2[1], one2, LS, false);                  \
    LS = __builtin_amdgcn_fdot2(PU.h2[2], one2, LS, false);                  \
    LS = __builtin_amdgcn_fdot2(PU.h2[3], one2, LS, false);
#else
#define LSUM(LS, PU)                                                         \
    _Pragma("unroll") for (int i = 0; i < 8; ++i) { LS += (float)PU.h8[i]; }
#endif

#define FRAG_BODY(QF, K0, K1, V0, V1, EB, O0, O1, LS)                        \
  {                                                                          \
    const f32x4 zz = {0.f, 0.f, 0.f, 0.f};                                   \
    f32x4 s0 = MFMA16(K0, QF, zz);   /* keys 8g+0..3 of col q16 */           \
    f32x4 s1 = MFMA16(K1, QF, zz);   /* keys 8g+4..7 */                      \
    union { fp16x2 h2[4]; half8 h8; } pu, eu;                                \
    eu.h8 = EB;                                                              \
    pu.h2[0] = __builtin_amdgcn_cvt_pkrtz(                                   \
        __builtin_amdgcn_exp2f(s0[0]), __builtin_amdgcn_exp2f(s0[1]));       \
    pu.h2[1] = __builtin_amdgcn_cvt_pkrtz(                                   \
        __builtin_amdgcn_exp2f(s0[2]), __builtin_amdgcn_exp2f(s0[3]));       \
    pu.h2[2] = __builtin_amdgcn_cvt_pkrtz(                                   \
        __builtin_amdgcn_exp2f(s1[0]), __builtin_amdgcn_exp2f(s1[1]));       \
    pu.h2[3] = __builtin_amdgcn_cvt_pkrtz(                                   \
        __builtin_amdgcn_exp2f(s1[2]), __builtin_amdgcn_exp2f(s1[3]));       \
    pu.h2[0] *= eu.h2[0];  pu.h2[1] *= eu.h2[1];   /* v_pk_mul_f16 */        \
    pu.h2[2] *= eu.h2[2];  pu.h2[3] *= eu.h2[3];                             \
    LSUM(LS, pu)                                                             \
    O0 = MFMA16(V0, pu.h8, O0);      /* O^T[4g+r][q16] */                    \
    O1 = MFMA16(V1, pu.h8, O1);      /* O^T[16+4g+r][q16] */                 \
  }

  half8 kA0 = *(const half8*)Kp0;
  half8 kA1 = *(const half8*)Kp1;
  half8 vA0 = *(const half8*)Vp0;
  half8 vA1 = *(const half8*)Vp1;
  half8 bA0 = *(const half8*)(Bp);
  half8 bA1 = *(const half8*)(Bp + 512);
  half8 bA2 = *(const half8*)(Bp + 1024);
  half8 bA3 = *(const half8*)(Bp + 1536);

  for (int kt = 0; kt < 31; ++kt) {
    size_t ko = (size_t)(kt + 1) * 1024;   // K: 32 keys * 32 d
    int    co = (kt + 1) * 32;             // V^T column offset
    const f16* Bn = Bp - ko;               // dy decreases with kt
    half8 kB0 = *(const half8*)(Kp0 + ko);
    half8 kB1 = *(const half8*)(Kp1 + ko);
    half8 vB0 = *(const half8*)(Vp0 + co);
    half8 vB1 = *(const half8*)(Vp1 + co);
    half8 bB0 = *(const half8*)(Bn);       // only 2 bias loads per kt:
    half8 bB1 = *(const half8*)(Bn + 512); // frag2/3(kt+1) = frag0/1(kt)
    // Pin the prefetch issue BEFORE the compute of tile kt.
    __builtin_amdgcn_sched_barrier(0);
    FRAG_BODY(qf0, kA0, kA1, vA0, vA1, bA0, o0a, o1a, lsa);
    FRAG_BODY(qf1, kA0, kA1, vA0, vA1, bA1, o0b, o1b, lsb);
    FRAG_BODY(qf2, kA0, kA1, vA0, vA1, bA2, o0c, o1c, lsc);
    FRAG_BODY(qf3, kA0, kA1, vA0, vA1, bA3, o0d, o1d, lsd);
    kA0 = kB0; kA1 = kB1; vA0 = vB0; vA1 = vB1;
    bA2 = bA0; bA3 = bA1;                  // register reuse (was 2 loads)
    bA0 = bB0; bA1 = bB1;
  }
  FRAG_BODY(qf0, kA0, kA1, vA0, vA1, bA0, o0a, o1a, lsa);
  FRAG_BODY(qf1, kA0, kA1, vA0, vA1, bA1, o0b, o1b, lsb);
  FRAG_BODY(qf2, kA0, kA1, vA0, vA1, bA2, o0c, o1c, lsc);
  FRAG_BODY(qf3, kA0, kA1, vA0, vA1, bA3, o0d, o1d, lsd);
#undef FRAG_BODY
#undef LSUM

  // ---- epilogue 1: normalized O^T -> LDS (swizzled) ----
  char* OsB = (char*)Os + h * 4096;
#define FRAG_OUT(O0, O1, LS, F)                                              \
  {                                                                          \
    float l = LS;                                                            \
    l += __shfl_xor(l, 16);                                                  \
    l += __shfl_xor(l, 32);                                                  \
    float invl = 1.0f / l;                                                   \
    int floc = (F) * 16 + q16;                                               \
    int swz = (floc & 7) << 4;                                               \
    half4 w0, w1;                                                            \
    _Pragma("unroll") for (int r = 0; r < 4; ++r) {                          \
      w0[r] = (f16)(O0[r] * invl); w1[r] = (f16)(O1[r] * invl);              \
    }                                                                        \
    *(half4*)(OsB + ((floc * 64 + g * 8) ^ swz)) = w0;                       \
    *(half4*)(OsB + ((floc * 64 + 32 + g * 8) ^ swz)) = w1;                  \
  }
  FRAG_OUT(o0a, o1a, lsa, 0);
  FRAG_OUT(o0b, o1b, lsb, 1);
  FRAG_OUT(o0c, o1c, lsc, 2);
  FRAG_OUT(o0d, o1d, lsd, 3);
#undef FRAG_OUT

  __syncthreads();

  // ---- epilogue 2: out-proj slice, cols [wave*32, wave*32+32) ----
  int cb = wave * 32;
  float bias0 = b_out[cb + q16];
  float bias1 = b_out[cb + 16 + q16];
  f32x4 acc[4][2] = {};
  const char* OsA = (const char*)Os;
#pragma unroll
  for (int kc = 0; kc < 8; ++kc) {         // k-chunk = head kc, d = 8g..+7
    half8 bf0 = *(const half8*)(Wto + (size_t)(cb + q16) * 256 + kc * 32 + g * 8);
    half8 bf1 = *(const half8*)(Wto + (size_t)(cb + 16 + q16) * 256 + kc * 32 + g * 8);
#pragma unroll
    for (int mf = 0; mf < 4; ++mf) {
      int row = mf * 16 + q16;
      half8 af = *(const half8*)(OsA + kc * 4096 +
                                 ((row * 64 + g * 16) ^ ((row & 7) << 4)));
      acc[mf][0] = MFMA16(af, bf0, acc[mf][0]);
      acc[mf][1] = MFMA16(af, bf1, acc[mf][1]);
    }
  }

#pragma unroll
  for (int mf = 0; mf < 4; ++mf) {
#pragma unroll
    for (int cf = 0; cf < 2; ++cf) {
      int c = cb + cf * 16 + q16;
      float bias = cf ? bias1 : bias0;
#pragma unroll
      for (int r = 0; r < 4; ++r) {
        int mm = (b << 10) + qbase + mf * 16 + g * 4 + r;
        out[(size_t)mm * 256 + c] = acc[mf][cf][r] + bias;
      }
    }
  }
}

extern "C" void kernel_launch(void* const* d_in, const int* in_sizes, int n_in,
                              void* d_out, int out_size, void* d_ws, size_t ws_size,
                              hipStream_t stream) {
  (void)in_sizes; (void)n_in; (void)out_size; (void)ws_size;
  const float* x        = (const float*)d_in[0];
  const float* W_qkv    = (const float*)d_in[1];
  const float* W_out    = (const float*)d_in[2];
  const float* b_out    = (const float*)d_in[3];
  const float* bias_tab = (const float*)d_in[4];
  float* out = (float*)d_out;
  char* ws = (char*)d_ws;

  f16* Qh  = (f16*)(ws);
  f16* Kh  = (f16*)(ws + (size_t)(8u  << 20));
  f16* Vt  = (f16*)(ws + (size_t)(16u << 20));
  f16* ebC = (f16*)(ws + (size_t)(24u << 20));
  f16* Wtq = (f16*)(ws + (size_t)(48u << 20));
  f16* Wto = (f16*)(ws + (size_t)(48u << 20) + 768 * 256 * 2);

  hipLaunchKernelGGL(prep_kernel, dim3(380), dim3(256), 0, stream,
                     W_qkv, W_out, bias_tab, Wtq, Wto, ebC);
  hipLaunchKernelGGL(qkv_kernel, dim3(256, 2), dim3(256), 0, stream,
                     x, Wtq, Qh, Kh, Vt);
  hipLaunchKernelGGL(attn_out_kernel, dim3(256), dim3(512), 0, stream,
                     Qh, Kh, Vt, ebC, Wto, b_out, out);
}